// Round 8
// baseline (15543.489 us; speedup 1.0000x reference)
//
#include <hip/hip_runtime.h>
#include <math.h>

// Problem constants (fixed by setup_inputs)
constexpr int U      = 128;   // UNITS
constexpr int G4     = 512;   // 4*U gate width
constexpr int NCls   = 10;    // classes
constexpr int TSTEPS = 1000;
constexpr int BATCH  = 256;
constexpr int CROWS  = 56;    // Wh0 rows cached in LDS (112 KB)

// ---------------------------------------------------------------------------
// Evidence ledger:
//  r0 naive per-use loads, 512 thr                     15.7 ms
//  r1-r3 big cross-barrier register streaming          29-30 ms (VGPR>128 spill)
//  r4 per-use + 4 accs + LN-fold + 4 barriers           8.57 ms
//  r5 NB=4 batching (grid 64)                          17.1 ms (idles CUs)
//  r6 1024 thr + partial-z + packed LDS cache           7.95 ms
//  r7 row-major dwordx4 weight streaming                7.09 ms (VALUBusy 36->22)
// r7 model: step 18.5 kcyc vs port floor ~10.5-12 kcyc -> ~6 kcyc of port-idle
// (gate serial windows, barrier drains, phase ramps). This version keeps r7's
// proven structure and adds SMALL counted prefetch (fits 128-VGPR budget,
// unlike r1-r3's monsters):
//   - 8 float4/thread of phase-C weights issued in the phase-B window
//   - 8 float4/thread of phase-A streamed rows (g>=3) issued in phase-D window
//   - Wh0 LDS cache 48 -> 56 rows (spare LDS), phase-A stream 160 -> 144 KB
// Kill signals: VGPR=128 + WRITE_SIZE >> 10 MB => spilled, revert.
// ---------------------------------------------------------------------------

__device__ __forceinline__ float sigm(float x) {
    return 1.0f / (1.0f + __expf(-x));
}

// k = time_gate(t, tau, s); floor-mod semantics matching jnp.mod
__device__ __forceinline__ float tgate(float t, float tau, float s) {
    float r = fmodf(t - s, tau);
    if (r < 0.0f) r += tau;
    const float phi = r / tau;
    return (phi < 0.025f) ? 40.0f * phi
         : (phi < 0.05f)  ? 2.0f - 40.0f * phi
         : 0.001f * phi;
}

// 4-row FMA block: ac.{x,y,z,w} are 4 output columns; hb broadcasts 4 rows.
#define ROW4(WP, I, HB) { \
    float4 w_; \
    w_ = (WP)[((I)+0)*128]; ac.x += (HB).x*w_.x; ac.y += (HB).x*w_.y; ac.z += (HB).x*w_.z; ac.w += (HB).x*w_.w; \
    w_ = (WP)[((I)+1)*128]; ac.x += (HB).y*w_.x; ac.y += (HB).y*w_.y; ac.z += (HB).y*w_.z; ac.w += (HB).y*w_.w; \
    w_ = (WP)[((I)+2)*128]; ac.x += (HB).z*w_.x; ac.y += (HB).z*w_.y; ac.z += (HB).z*w_.z; ac.w += (HB).z*w_.w; \
    w_ = (WP)[((I)+3)*128]; ac.x += (HB).w*w_.x; ac.y += (HB).w*w_.y; ac.z += (HB).w*w_.z; ac.w += (HB).w*w_.w; }

// Same, with 4 pre-loaded weight float4s (prefetched in an earlier window).
#define ROW4P(W0, W1, W2, W3, HB) { \
    ac.x += (HB).x*(W0).x; ac.y += (HB).x*(W0).y; ac.z += (HB).x*(W0).z; ac.w += (HB).x*(W0).w; \
    ac.x += (HB).y*(W1).x; ac.y += (HB).y*(W1).y; ac.z += (HB).y*(W1).z; ac.w += (HB).y*(W1).w; \
    ac.x += (HB).z*(W2).x; ac.y += (HB).z*(W2).y; ac.z += (HB).z*(W2).z; ac.w += (HB).z*(W2).w; \
    ac.x += (HB).w*(W3).x; ac.y += (HB).w*(W3).y; ac.z += (HB).w*(W3).z; ac.w += (HB).w*(W3).w; }

__global__ __launch_bounds__(1024, 1) void plstm_fused(
    const float* __restrict__ inputs,  // [B,T,3]
    const float* __restrict__ times,   // [B,T]
    const float* __restrict__ Wx0,     // [3,512]
    const float* __restrict__ Wh0,     // [128,512]
    const float* __restrict__ b0,      // [512]
    const float* __restrict__ tau0,    // [128]
    const float* __restrict__ s0,      // [128]
    const float* __restrict__ Wx1,     // [128,512]
    const float* __restrict__ Wh1,     // [128,512]
    const float* __restrict__ b1,      // [512]
    const float* __restrict__ tau1,    // [128]
    const float* __restrict__ s1,      // [128]
    const float* __restrict__ gamma_,  // [128]
    const float* __restrict__ beta_,   // [128]
    const float* __restrict__ Wfc,     // [128,10]
    const float* __restrict__ bfc,     // [10]
    float* __restrict__ out)           // [B,T,10]
{
    const int tid = threadIdx.x;        // 0..1023
    const int c4  = tid & 127;          // column quad (cols 4c4..4c4+3)
    const int g   = tid >> 7;           // rowgroup 0..7
    const int b   = blockIdx.x;

    __shared__ __align__(16) float wh0c[CROWS * G4];   // 112 KB (rows 0..55)
    __shared__ __align__(16) float zu[8 * G4];         // 16 KB partial-z union
    __shared__ __align__(16) float h0s[U];             // h0 state
    __shared__ __align__(16) float ghu[2 * U];         // [0..127]=gamma*h0, [128..255]=h1
    __shared__ __align__(16) float b0s[G4], b1s[G4], Ps[G4], Qs[G4];
    __shared__ __align__(16) float wx0s[3 * G4];
    __shared__ __align__(16) float wfcs[U * 11];       // stride 11
    __shared__ float bfcs[NCls];
    __shared__ float red[4];                           // {sum0,sq0,sum1,sq1}
    __shared__ float gms[U], bts[U];

    // ---- prologue: stage everything ----
    if (tid < U) { gms[tid] = gamma_[tid]; bts[tid] = beta_[tid];
                   h0s[tid] = 0.f; ghu[tid] = 0.f; ghu[U + tid] = 0.f; }
    {   // Wh0 rows 0..55 contiguous: 7168 float4 = 7 per thread
        float4* dst = reinterpret_cast<float4*>(wh0c);
        const float4* src = reinterpret_cast<const float4*>(Wh0);
        #pragma unroll
        for (int i = 0; i < 7; ++i) dst[tid + i * 1024] = src[tid + i * 1024];
    }
    if (tid < G4) { b0s[tid] = b0[tid]; b1s[tid] = b1[tid]; }
    for (int i = tid; i < 3 * G4; i += 1024) wx0s[i] = Wx0[i];
    for (int i = tid; i < U * NCls; i += 1024) {
        const int u = i / NCls, c = i - u * NCls;
        wfcs[u * 11 + c] = Wfc[i];
    }
    if (tid < NCls) bfcs[tid] = bfc[tid];
    __syncthreads();

    // ---- LN fold constants per column: P[j]=sum beta[u]*Wx1[u][j],
    //      Q[j]=sum gamma[u]*Wx1[u][j] (threads 0..511, coalesced) ----
    if (tid < G4) {
        float P = 0.f, Q = 0.f;
        #pragma unroll 8
        for (int u = 0; u < U; ++u) {
            const float w = Wx1[u * G4 + tid];
            Q += gms[u] * w;
            P += bts[u] * w;
        }
        Ps[tid] = P; Qs[tid] = Q;
    }

    // ---- per-thread persistent parameters (gate threads only) ----
    float tau0r = 0.f, s0r = 0.f, tau1r = 0.f, s1r = 0.f, gr = 0.f;
    if (tid < U) {
        tau0r = tau0[tid]; s0r = s0[tid];
        tau1r = tau1[tid]; s1r = s1[tid];
        gr = gms[tid];
    }
    float c0r = 0.f, c1r = 0.f, h0r = 0.f, h1r = 0.f;

    // ---- loop-invariant bases ----
    // Phase A: rows paBase..paBase+7 are register-prefetched each step (g>=3);
    //          g==3 additionally reads cached rows 48..55 from LDS;
    //          g>=4 additionally streams rows g*16+8..+15.
    const int paBase = (g == 3) ? 56 : g * 16;
    const float4* __restrict__ wpA =
        reinterpret_cast<const float4*>(Wh0) + paBase * 128 + c4;
    // Phase C: half 0 = Wx1 x (gamma*h0), half 1 = Wh1 x h1; 32 rows each rg.
    const int half = tid >> 9;
    const int rgC  = (tid >> 7) & 3;
    const int r0C  = rgC * 32;
    const float4* __restrict__ wpC =
        reinterpret_cast<const float4*>(half ? Wh1 : Wx1) + r0C * 128 + c4;
    const float* __restrict__ hvpC = ghu + half * U + r0C;

    const float* __restrict__ xp = inputs + (size_t)b * TSTEPS * 3;
    const float* __restrict__ tp = times  + (size_t)b * TSTEPS;
    float*       __restrict__ op = out    + (size_t)b * TSTEPS * NCls;

    float xa0 = xp[0], xa1 = xp[1], xa2 = xp[2], tva = tp[0];

    // ---- initial phase-A prefetch (t=0), g>=3 only ----
    float4 pa0, pa1, pa2, pa3, pa4, pa5, pa6, pa7;
    if (g >= 3) {
        pa0 = wpA[0 * 128]; pa1 = wpA[1 * 128];
        pa2 = wpA[2 * 128]; pa3 = wpA[3 * 128];
        pa4 = wpA[4 * 128]; pa5 = wpA[5 * 128];
        pa6 = wpA[6 * 128]; pa7 = wpA[7 * 128];
    }

    __syncthreads();

    for (int t = 0; t < TSTEPS; ++t) {
        const float x0 = xa0, x1 = xa1, x2 = xa2, tv = tva;
        const int tn = (t + 1 < TSTEPS) ? t + 1 : t;
        xa0 = xp[tn*3+0]; xa1 = xp[tn*3+1]; xa2 = xp[tn*3+2]; tva = tp[tn];

        // ---- phase A: matvec0 partials (cached + prefetched + streamed) ----
        {
            float4 ac = make_float4(0.f, 0.f, 0.f, 0.f);
            if (g < 3) {
                const float4* wp = reinterpret_cast<const float4*>(wh0c) + g * 16 * 128 + c4;
                #pragma unroll
                for (int i = 0; i < 16; i += 4) {
                    const float4 hb = *reinterpret_cast<const float4*>(&h0s[g * 16 + i]);
                    ROW4(wp, i, hb);
                }
            } else {
                {   // prefetched rows paBase..paBase+7
                    const float4 hb0 = *reinterpret_cast<const float4*>(&h0s[paBase]);
                    ROW4P(pa0, pa1, pa2, pa3, hb0);
                    const float4 hb1 = *reinterpret_cast<const float4*>(&h0s[paBase + 4]);
                    ROW4P(pa4, pa5, pa6, pa7, hb1);
                }
                if (g == 3) {   // cached rows 48..55
                    const float4* wp = reinterpret_cast<const float4*>(wh0c) + 48 * 128 + c4;
                    #pragma unroll
                    for (int i = 0; i < 8; i += 4) {
                        const float4 hb = *reinterpret_cast<const float4*>(&h0s[48 + i]);
                        ROW4(wp, i, hb);
                    }
                } else {        // streamed rows g*16+8..+15
                    #pragma unroll
                    for (int i = 8; i < 16; i += 4) {
                        const float4 hb = *reinterpret_cast<const float4*>(&h0s[g * 16 + i]);
                        ROW4(wpA, i, hb);
                    }
                }
            }
            *reinterpret_cast<float4*>(&zu[g * G4 + 4 * c4]) = ac;
        }
        __syncthreads();                                   // B1

        // ---- phase B: gates0 + LN partials (threads 0..127) ----
        if (tid < U) {
            const int u = tid;
            float z[4];
            #pragma unroll
            for (int q = 0; q < 4; ++q) {
                const int c = u + q * 128;
                float s = b0s[c] + x0 * wx0s[c] + x1 * wx0s[G4 + c] + x2 * wx0s[2 * G4 + c];
                #pragma unroll
                for (int gg = 0; gg < 8; ++gg) s += zu[gg * G4 + c];
                z[q] = s;
            }
            const float ig = sigm(z[0]);
            const float fg = sigm(z[1]);
            const float gg = tanhf(z[2]);
            const float og = sigm(z[3]);
            const float ch = fg * c0r + ig * gg;
            const float hh = og * tanhf(ch);
            const float k  = tgate(tv, tau0r, s0r);
            const float hn = k * hh + (1.0f - k) * h0r;
            c0r = k * ch + (1.0f - k) * c0r;
            h0r = hn;
            h0s[u] = hn;
            ghu[u] = gr * hn;
            float ssum = hn, qsum = hn * hn;               // one-pass variance
            #pragma unroll
            for (int off = 1; off < 64; off <<= 1) {
                ssum += __shfl_xor(ssum, off);
                qsum += __shfl_xor(qsum, off);
            }
            if ((tid & 63) == 0) {
                red[(tid >> 6) * 2]     = ssum;
                red[(tid >> 6) * 2 + 1] = qsum;
            }
        }
        // ---- phase-C head prefetch (all threads; port busy during gates0) ----
        const float4 pc0 = wpC[0 * 128], pc1 = wpC[1 * 128],
                     pc2 = wpC[2 * 128], pc3 = wpC[3 * 128],
                     pc4 = wpC[4 * 128], pc5 = wpC[5 * 128],
                     pc6 = wpC[6 * 128], pc7 = wpC[7 * 128];
        __syncthreads();                                   // B2

        // ---- phase C: matvec1 partials (prefetched head + streamed body) ----
        {
            float4 ac = make_float4(0.f, 0.f, 0.f, 0.f);
            {
                const float4 hb0 = *reinterpret_cast<const float4*>(&hvpC[0]);
                ROW4P(pc0, pc1, pc2, pc3, hb0);
                const float4 hb1 = *reinterpret_cast<const float4*>(&hvpC[4]);
                ROW4P(pc4, pc5, pc6, pc7, hb1);
            }
            #pragma unroll 3
            for (int i = 8; i < 32; i += 4) {
                const float4 hb = *reinterpret_cast<const float4*>(&hvpC[i]);
                ROW4(wpC, i, hb);
            }
            *reinterpret_cast<float4*>(&zu[(half * 4 + rgC) * G4 + 4 * c4]) = ac;
        }
        __syncthreads();                                   // B3

        // ---- phase D: gates1 with LN fold (threads 0..127) ----
        if (tid < U) {
            const float mu    = (red[0] + red[2]) * (1.0f / 128.0f);
            const float msq   = (red[1] + red[3]) * (1.0f / 128.0f);
            const float rstd  = rsqrtf(msq - mu * mu + 1e-3f);
            const float murstd = mu * rstd;
            const int u = tid;
            float z[4];
            #pragma unroll
            for (int q = 0; q < 4; ++q) {
                const int c = u + q * 128;
                const float sx = (zu[0*G4+c] + zu[1*G4+c]) + (zu[2*G4+c] + zu[3*G4+c]);
                const float sh = (zu[4*G4+c] + zu[5*G4+c]) + (zu[6*G4+c] + zu[7*G4+c]);
                // z1 = b1 + P + rstd*Swx - mu*rstd*Q + Swh (exact LN fold)
                z[q] = b1s[c] + Ps[c] + rstd * sx - murstd * Qs[c] + sh;
            }
            const float ig = sigm(z[0]);
            const float fg = sigm(z[1]);
            const float gg = tanhf(z[2]);
            const float og = sigm(z[3]);
            const float ch = fg * c1r + ig * gg;
            const float hh = og * tanhf(ch);
            const float k  = tgate(tv, tau1r, s1r);
            const float hn = k * hh + (1.0f - k) * h1r;
            c1r = k * ch + (1.0f - k) * c1r;
            h1r = hn;
            ghu[U + u] = hn;                               // h1 state
        }
        // ---- next-step phase-A prefetch (g>=3; port busy during gates1) ----
        if (g >= 3) {
            pa0 = wpA[0 * 128]; pa1 = wpA[1 * 128];
            pa2 = wpA[2 * 128]; pa3 = wpA[3 * 128];
            pa4 = wpA[4 * 128]; pa5 = wpA[5 * 128];
            pa6 = wpA[6 * 128]; pa7 = wpA[7 * 128];
        }
        __syncthreads();                                   // B4

        // ---- phase E: FC + softmax (wave 0); other waves roll into t+1 ----
        if (tid < 64) {
            const float a  = ghu[U + tid];
            const float bv = ghu[U + tid + 64];
            float p[NCls];
            #pragma unroll
            for (int c = 0; c < NCls; ++c)
                p[c] = a * wfcs[tid * 11 + c] + bv * wfcs[(tid + 64) * 11 + c];
            #pragma unroll
            for (int off = 1; off < 64; off <<= 1) {
                #pragma unroll
                for (int c = 0; c < NCls; ++c) p[c] += __shfl_xor(p[c], off);
            }
            float m = -1e30f;
            #pragma unroll
            for (int c = 0; c < NCls; ++c) { p[c] += bfcs[c]; m = fmaxf(m, p[c]); }
            float ssum = 0.0f;
            #pragma unroll
            for (int c = 0; c < NCls; ++c) { p[c] = __expf(p[c] - m); ssum += p[c]; }
            const float inv = 1.0f / ssum;
            float pv = p[0];               // static-index select (no scratch)
            #pragma unroll
            for (int c = 1; c < NCls; ++c) if (tid == c) pv = p[c];
            if (tid < NCls) op[t * NCls + tid] = pv * inv;
        }
        // No trailing barrier: phase A(t+1) writes zu (last read in D before
        // B4) and reads h0s (written in B before B2); phase E reads only
        // ghu[128..]/wfcs, rewritten next in D(t+1) behind 3 barriers.
    }
}

extern "C" void kernel_launch(void* const* d_in, const int* in_sizes, int n_in,
                              void* d_out, int out_size, void* d_ws, size_t ws_size,
                              hipStream_t stream) {
    const float* inputs = (const float*)d_in[0];
    const float* times  = (const float*)d_in[1];
    const float* Wx0    = (const float*)d_in[2];
    const float* Wh0    = (const float*)d_in[3];
    const float* b0     = (const float*)d_in[4];
    const float* tau0   = (const float*)d_in[5];
    const float* s0     = (const float*)d_in[6];
    const float* Wx1    = (const float*)d_in[7];
    const float* Wh1    = (const float*)d_in[8];
    const float* b1     = (const float*)d_in[9];
    const float* tau1   = (const float*)d_in[10];
    const float* s1     = (const float*)d_in[11];
    const float* gamma_ = (const float*)d_in[12];
    const float* beta_  = (const float*)d_in[13];
    const float* Wfc    = (const float*)d_in[14];
    const float* bfc    = (const float*)d_in[15];
    float* out = (float*)d_out;

    dim3 grid(BATCH);
    dim3 block(1024);
    hipLaunchKernelGGL(plstm_fused, grid, block, 0, stream,
                       inputs, times, Wx0, Wh0, b0, tau0, s0,
                       Wx1, Wh1, b1, tau1, s1, gamma_, beta_, Wfc, bfc, out);
}

// Round 9
// 9451.520 us; speedup vs baseline: 1.6445x; 1.6445x over previous
//
#include <hip/hip_runtime.h>
#include <math.h>

// Problem constants (fixed by setup_inputs)
constexpr int U      = 128;   // UNITS
constexpr int G4     = 512;   // 4*U gate width
constexpr int NCls   = 10;    // classes
constexpr int TSTEPS = 1000;
constexpr int BATCH  = 256;

// ---------------------------------------------------------------------------
// Evidence ledger:
//  r0 naive per-use loads, 512 thr                15.7 ms
//  r1-r3 cross-barrier register streaming         29-30 ms
//  r4 per-use + 4 accs + LN-fold + 4 barriers      8.57 ms
//  r5 NB=4 batching (grid 64)                     17.1 ms
//  r6 1024 thr + partial-z + packed LDS cache      7.95 ms
//  r7 row-major dwordx4 weight streaming           7.09 ms   <- best
//  r8 16 float4 register prefetch across barriers 15.5 ms (scratch spill)
// IRON LAW (r1,r2,r3,r8): VGPR live ranges crossing __syncthreads() are
// demoted to scratch by this allocator regardless of demand. Only LDS and a
// few scalars may cross barriers.
// This version: 2 barriers/step + wave-role split so the L1 port never idles:
//   W1 (B2->B1): half-1 waves run gates1(t-1) while half-0 issues phase-A
//                loads; then all do phase A -> zu0.
//   W2 (B1->B2): half-0 waves run gates0(t) while half-1 issues phase-C Wh1
//                loads; then all do phase C -> zu1. Wave 0 also runs the
//                (deferred) FC/softmax for step t-1.
// Gate state is replicated per wave-pair (32 units each) in registers
// (scalars only). LN stats cross B2 via red[8]. All weight loads per-use.
// ---------------------------------------------------------------------------

__device__ __forceinline__ float sigm(float x) {
    return 1.0f / (1.0f + __expf(-x));
}

// k = time_gate(t, tau, s); floor-mod semantics matching jnp.mod
__device__ __forceinline__ float tgate(float t, float tau, float s) {
    float r = fmodf(t - s, tau);
    if (r < 0.0f) r += tau;
    const float phi = r / tau;
    return (phi < 0.025f) ? 40.0f * phi
         : (phi < 0.05f)  ? 2.0f - 40.0f * phi
         : 0.001f * phi;
}

// 4-row FMA block: ac.{x,y,z,w} are 4 output columns; hb broadcasts 4 rows.
#define ROW4(WP, I, HB) { \
    float4 w_; \
    w_ = (WP)[((I)+0)*128]; ac.x += (HB).x*w_.x; ac.y += (HB).x*w_.y; ac.z += (HB).x*w_.z; ac.w += (HB).x*w_.w; \
    w_ = (WP)[((I)+1)*128]; ac.x += (HB).y*w_.x; ac.y += (HB).y*w_.y; ac.z += (HB).y*w_.z; ac.w += (HB).y*w_.w; \
    w_ = (WP)[((I)+2)*128]; ac.x += (HB).z*w_.x; ac.y += (HB).z*w_.y; ac.z += (HB).z*w_.z; ac.w += (HB).z*w_.w; \
    w_ = (WP)[((I)+3)*128]; ac.x += (HB).w*w_.x; ac.y += (HB).w*w_.y; ac.z += (HB).w*w_.z; ac.w += (HB).w*w_.w; }

__global__ __launch_bounds__(1024, 1) void plstm_fused(
    const float* __restrict__ inputs,  // [B,T,3]
    const float* __restrict__ times,   // [B,T]
    const float* __restrict__ Wx0,     // [3,512]
    const float* __restrict__ Wh0,     // [128,512]
    const float* __restrict__ b0,      // [512]
    const float* __restrict__ tau0,    // [128]
    const float* __restrict__ s0,      // [128]
    const float* __restrict__ Wx1,     // [128,512]
    const float* __restrict__ Wh1,     // [128,512]
    const float* __restrict__ b1,      // [512]
    const float* __restrict__ tau1,    // [128]
    const float* __restrict__ s1,      // [128]
    const float* __restrict__ gamma_,  // [128]
    const float* __restrict__ beta_,   // [128]
    const float* __restrict__ Wfc,     // [128,10]
    const float* __restrict__ bfc,     // [10]
    float* __restrict__ out)           // [B,T,10]
{
    const int tid  = threadIdx.x;       // 0..1023
    const int lane = tid & 63;
    const int wv   = tid >> 6;          // wave 0..15
    const int c4   = tid & 127;         // column quad (phase A/C)
    const int g    = tid >> 7;          // rowgroup 0..7 (phase A)
    const int half = tid >> 9;          // 0: waves 0-7, 1: waves 8-15
    const int rgC  = (tid >> 7) & 3;    // phase-C rowgroup (32 rows)
    const int b    = blockIdx.x;

    __shared__ __align__(16) float wh0c[32 * G4];      // 64 KB: Wh0 rows 0..31
    __shared__ __align__(16) float zu0[8 * G4];        // 16 KB layer-0 partials
    __shared__ __align__(16) float zu1[8 * G4];        // 16 KB layer-1 partials
    __shared__ __align__(16) float h0s[U];             // h0 state (B'->A, crosses B2)
    __shared__ __align__(16) float h1s[U];             // h1 state (D'->E, crosses B1)
    __shared__ __align__(16) float gh0w[8][32];        // wave-private gamma*h0 (B'->C)
    __shared__ __align__(16) float h1w[8][32];         // wave-private h1 (D'->C)
    __shared__ __align__(16) float b0s[G4], b1s[G4], Ps[G4], Qs[G4];
    __shared__ __align__(16) float wx0s[3 * G4];
    __shared__ __align__(16) float wfcs[U * 11];       // stride 11
    __shared__ float bfcs[NCls];
    __shared__ float red[8];                           // LN partials, cross B2
    __shared__ float gms[U], bts[U];

    // ---- prologue: stage everything ----
    if (tid < U) { gms[tid] = gamma_[tid]; bts[tid] = beta_[tid];
                   h0s[tid] = 0.f; h1s[tid] = 0.f; }
    if (tid < 256) { ((float*)h1w)[tid] = 0.f; }       // zero h1w (C(0) reads it)
    {   // Wh0 rows 0..31: 4096 float4, 4 per thread
        float4* dst = reinterpret_cast<float4*>(wh0c);
        const float4* src = reinterpret_cast<const float4*>(Wh0);
        #pragma unroll
        for (int i = 0; i < 4; ++i) dst[tid + i * 1024] = src[tid + i * 1024];
    }
    if (tid < G4) { b0s[tid] = b0[tid]; b1s[tid] = b1[tid]; }
    for (int i = tid; i < 3 * G4; i += 1024) wx0s[i] = Wx0[i];
    for (int i = tid; i < U * NCls; i += 1024) {
        const int u = i / NCls, c = i - u * NCls;
        wfcs[u * 11 + c] = Wfc[i];
    }
    if (tid < NCls) bfcs[tid] = bfc[tid];
    __syncthreads();

    // ---- LN fold constants per column: P[j]=sum beta[u]*Wx1[u][j],
    //      Q[j]=sum gamma[u]*Wx1[u][j] ----
    if (tid < G4) {
        float P = 0.f, Q = 0.f;
        #pragma unroll 8
        for (int u = 0; u < U; ++u) {
            const float w = Wx1[u * G4 + tid];
            Q += gms[u] * w;
            P += bts[u] * w;
        }
        Ps[tid] = P; Qs[tid] = Q;
    }

    // ---- per-lane replicated gate state (scalars only cross barriers) ----
    // half-0 wave wv (0..7): gates0 for units 32*(wv>>1) + (lane&31)
    // half-1 wave wv (8..15): gates1 for units 32*((wv-8)>>1) + (lane&31)
    const int rg0 = (half == 0) ? (wv >> 1) : 0;
    const int rg1 = (half == 1) ? ((wv - 8) >> 1) : 0;
    const int um  = ((half == 0) ? rg0 : rg1) * 32 + (lane & 31);  // my unit
    float tauM = 0.f, sM = 0.f, grM = 0.f;
    if (half == 0) { tauM = tau0[um]; sM = s0[um]; grM = gamma_[um]; }
    else           { tauM = tau1[um]; sM = s1[um]; }
    float cM = 0.f, hM = 0.f;   // replicated cell / hidden state of unit um

    // ---- loop-invariant bases ----
    const float4* __restrict__ wpA =
        reinterpret_cast<const float4*>(Wh0) + g * 16 * 128 + c4;     // g>=2 stream
    const float4* __restrict__ wpAc =
        reinterpret_cast<const float4*>(wh0c) + g * 16 * 128 + c4;    // g<2 cached
    const float4* __restrict__ wpC =
        reinterpret_cast<const float4*>(half ? Wh1 : Wx1) + rgC * 32 * 128 + c4;
    const float* __restrict__ hvC = half ? &h1w[wv - 8][0] : &gh0w[wv][0];

    const float* __restrict__ xp = inputs + (size_t)b * TSTEPS * 3;
    const float* __restrict__ tp = times  + (size_t)b * TSTEPS;
    float*       __restrict__ op = out    + (size_t)b * TSTEPS * NCls;

    float xa0 = xp[0], xa1 = xp[1], xa2 = xp[2], tva = tp[0];
    float tvp = 0.f;   // previous step's t (for deferred gates1)

    __syncthreads();

    for (int t = 0; t < TSTEPS; ++t) {
        const float x0 = xa0, x1 = xa1, x2 = xa2, tv = tva;
        const int tn = (t + 1 < TSTEPS) ? t + 1 : t;
        xa0 = xp[tn*3+0]; xa1 = xp[tn*3+1]; xa2 = xp[tn*3+2]; tva = tp[tn];

        // ================= window W1 (after B2(t-1)) =================
        // half-1: gates1(t-1)  [reads zu1(t-1) + red(t-1), both cross B2]
        if (half == 1 && t > 0) {
            const float mu   = (red[0]+red[2]+red[4]+red[6]) * (1.0f/256.0f);
            const float msq  = (red[1]+red[3]+red[5]+red[7]) * (1.0f/256.0f);
            const float rstd = rsqrtf(msq - mu*mu + 1e-3f);
            const float murstd = mu * rstd;
            float z[4];
            #pragma unroll
            for (int q = 0; q < 4; ++q) {
                const int c = um + q * 128;
                const float sx = (zu1[0*G4+c] + zu1[1*G4+c]) + (zu1[2*G4+c] + zu1[3*G4+c]);
                const float sh = (zu1[4*G4+c] + zu1[5*G4+c]) + (zu1[6*G4+c] + zu1[7*G4+c]);
                z[q] = b1s[c] + Ps[c] + rstd * sx - murstd * Qs[c] + sh;
            }
            const float ig = sigm(z[0]), fg = sigm(z[1]);
            const float gg = tanhf(z[2]), og = sigm(z[3]);
            const float ch = fg * cM + ig * gg;
            const float hh = og * tanhf(ch);
            const float k  = tgate(tvp, tauM, sM);
            const float hn = k * hh + (1.0f - k) * hM;
            cM = k * ch + (1.0f - k) * cM;
            hM = hn;
            if (lane < 32) { h1w[wv - 8][lane] = hn; h1s[um] = hn; }
        }
        // phase A (all waves): zu0(t) partials  [reads h0s(t-1), crossed B2]
        {
            float4 ac = make_float4(0.f, 0.f, 0.f, 0.f);
            const float4* wp = (g < 2) ? wpAc : wpA;
            #pragma unroll
            for (int i = 0; i < 16; i += 4) {
                const float4 hb = *reinterpret_cast<const float4*>(&h0s[g * 16 + i]);
                ROW4(wp, i, hb);
            }
            *reinterpret_cast<float4*>(&zu0[g * G4 + 4 * c4]) = ac;
        }
        __syncthreads();                                   // ===== B1 =====

        // ================= window W2 =================
        // wave 0: deferred FC+softmax for step t-1 [reads h1s, crossed B1]
        if (wv == 0 && t > 0) {
            const float a  = h1s[lane];
            const float bv = h1s[lane + 64];
            float p[NCls];
            #pragma unroll
            for (int c = 0; c < NCls; ++c)
                p[c] = a * wfcs[lane * 11 + c] + bv * wfcs[(lane + 64) * 11 + c];
            #pragma unroll
            for (int off = 1; off < 64; off <<= 1) {
                #pragma unroll
                for (int c = 0; c < NCls; ++c) p[c] += __shfl_xor(p[c], off);
            }
            float m = -1e30f;
            #pragma unroll
            for (int c = 0; c < NCls; ++c) { p[c] += bfcs[c]; m = fmaxf(m, p[c]); }
            float ssum = 0.0f;
            #pragma unroll
            for (int c = 0; c < NCls; ++c) { p[c] = __expf(p[c] - m); ssum += p[c]; }
            const float inv = 1.0f / ssum;
            float pv = p[0];
            #pragma unroll
            for (int c = 1; c < NCls; ++c) if (lane == c) pv = p[c];
            if (lane < NCls) op[(t - 1) * NCls + lane] = pv * inv;
        }
        // half-0: gates0(t)  [reads zu0(t), crossed B1; writes h0s (read after
        // next B2), gh0w (own wave, read below), red (read after B2)]
        if (half == 0) {
            float z[4];
            #pragma unroll
            for (int q = 0; q < 4; ++q) {
                const int c = um + q * 128;
                float s = b0s[c] + x0 * wx0s[c] + x1 * wx0s[G4 + c] + x2 * wx0s[2*G4 + c];
                s += (zu0[0*G4+c] + zu0[1*G4+c]) + (zu0[2*G4+c] + zu0[3*G4+c]);
                s += (zu0[4*G4+c] + zu0[5*G4+c]) + (zu0[6*G4+c] + zu0[7*G4+c]);
                z[q] = s;
            }
            const float ig = sigm(z[0]), fg = sigm(z[1]);
            const float gg = tanhf(z[2]), og = sigm(z[3]);
            const float ch = fg * cM + ig * gg;
            const float hh = og * tanhf(ch);
            const float k  = tgate(tv, tauM, sM);
            const float hn = k * hh + (1.0f - k) * hM;
            cM = k * ch + (1.0f - k) * cM;
            hM = hn;
            if (lane < 32) { h0s[um] = hn; gh0w[wv][lane] = grM * hn; }
            float ssum = hn, qsum = hn * hn;   // each unit counted twice -> /256
            #pragma unroll
            for (int off = 1; off < 64; off <<= 1) {
                ssum += __shfl_xor(ssum, off);
                qsum += __shfl_xor(qsum, off);
            }
            if (lane == 0) { red[2 * rg0] = ssum; red[2 * rg0 + 1] = qsum; }
        }
        // phase C (all waves): zu1(t) partials
        //   half 0: Wx1 rows 32rgC.. x gh0w (own wave, lgkmcnt-ordered)
        //   half 1: Wh1 rows 32rgC.. x h1w  (own wave, written in W1 / last step)
        {
            float4 ac = make_float4(0.f, 0.f, 0.f, 0.f);
            #pragma unroll 4
            for (int i = 0; i < 32; i += 4) {
                const float4 hb = *reinterpret_cast<const float4*>(&hvC[i]);
                ROW4(wpC, i, hb);
            }
            *reinterpret_cast<float4*>(&zu1[(half * 4 + rgC) * G4 + 4 * c4]) = ac;
        }
        tvp = tv;
        __syncthreads();                                   // ===== B2 =====
    }

    // ---- epilogue: gates1(T-1) then FC/softmax(T-1) ----
    if (half == 1) {
        const float mu   = (red[0]+red[2]+red[4]+red[6]) * (1.0f/256.0f);
        const float msq  = (red[1]+red[3]+red[5]+red[7]) * (1.0f/256.0f);
        const float rstd = rsqrtf(msq - mu*mu + 1e-3f);
        const float murstd = mu * rstd;
        float z[4];
        #pragma unroll
        for (int q = 0; q < 4; ++q) {
            const int c = um + q * 128;
            const float sx = (zu1[0*G4+c] + zu1[1*G4+c]) + (zu1[2*G4+c] + zu1[3*G4+c]);
            const float sh = (zu1[4*G4+c] + zu1[5*G4+c]) + (zu1[6*G4+c] + zu1[7*G4+c]);
            z[q] = b1s[c] + Ps[c] + rstd * sx - murstd * Qs[c] + sh;
        }
        const float ig = sigm(z[0]), fg = sigm(z[1]);
        const float gg = tanhf(z[2]), og = sigm(z[3]);
        const float ch = fg * cM + ig * gg;
        const float hh = og * tanhf(ch);
        const float k  = tgate(tvp, tauM, sM);
        const float hn = k * hh + (1.0f - k) * hM;
        if (lane < 32) h1s[um] = hn;
    }
    __syncthreads();
    if (wv == 0) {
        const float a  = h1s[lane];
        const float bv = h1s[lane + 64];
        float p[NCls];
        #pragma unroll
        for (int c = 0; c < NCls; ++c)
            p[c] = a * wfcs[lane * 11 + c] + bv * wfcs[(lane + 64) * 11 + c];
        #pragma unroll
        for (int off = 1; off < 64; off <<= 1) {
            #pragma unroll
            for (int c = 0; c < NCls; ++c) p[c] += __shfl_xor(p[c], off);
        }
        float m = -1e30f;
        #pragma unroll
        for (int c = 0; c < NCls; ++c) { p[c] += bfcs[c]; m = fmaxf(m, p[c]); }
        float ssum = 0.0f;
        #pragma unroll
        for (int c = 0; c < NCls; ++c) { p[c] = __expf(p[c] - m); ssum += p[c]; }
        const float inv = 1.0f / ssum;
        float pv = p[0];
        #pragma unroll
        for (int c = 1; c < NCls; ++c) if (lane == c) pv = p[c];
        if (lane < NCls) op[(TSTEPS - 1) * NCls + lane] = pv * inv;
    }
}

extern "C" void kernel_launch(void* const* d_in, const int* in_sizes, int n_in,
                              void* d_out, int out_size, void* d_ws, size_t ws_size,
                              hipStream_t stream) {
    const float* inputs = (const float*)d_in[0];
    const float* times  = (const float*)d_in[1];
    const float* Wx0    = (const float*)d_in[2];
    const float* Wh0    = (const float*)d_in[3];
    const float* b0     = (const float*)d_in[4];
    const float* tau0   = (const float*)d_in[5];
    const float* s0     = (const float*)d_in[6];
    const float* Wx1    = (const float*)d_in[7];
    const float* Wh1    = (const float*)d_in[8];
    const float* b1     = (const float*)d_in[9];
    const float* tau1   = (const float*)d_in[10];
    const float* s1     = (const float*)d_in[11];
    const float* gamma_ = (const float*)d_in[12];
    const float* beta_  = (const float*)d_in[13];
    const float* Wfc    = (const float*)d_in[14];
    const float* bfc    = (const float*)d_in[15];
    float* out = (float*)d_out;

    dim3 grid(BATCH);
    dim3 block(1024);
    hipLaunchKernelGGL(plstm_fused, grid, block, 0, stream,
                       inputs, times, Wx0, Wh0, b0, tau0, s0,
                       Wx1, Wh1, b1, tau1, s1, gamma_, beta_, Wfc, bfc, out);
}